// Round 1
// baseline (120.350 us; speedup 1.0000x reference)
//
#include <hip/hip_runtime.h>

// Problem constants (fixed by reference)
#define BS      16
#define CIN     32
#define COUT    64
#define OUT_DIM 1024
#define RS4     1024           // float4 per (.,c) row of length 4096 floats

// Tiling: one float4 = one patch (K=4). Block = 8 o x 32 patches, all 16 b.
#define OT      8              // o per block
#define PT      32             // patches (float4 columns) per block
// grid = (64/OT) * (1024/PT) = 8 * 32 = 256 blocks = 1 per CU

// out[b,o,p] = (1/sqrt(32)) * sum_{c,k} x[b,c,4p+k] * w[o,c,4p+k]
//
// v4: reuse-per-register redesign. v3 was per-CU byte-throughput bound:
//   VMEM 640 KB/CU (x o-reuse only 4) and LDS 1.15 MB/CU (w b-reuse only 2).
// Now each thread owns 4 b x 8 o x 1 patch for a quarter of c (c-split 4,
// c == cs mod 4), so:
//   - x VMEM halves: 256 KB/CU (each x float4 feeds 8 o's in-register)
//   - LDS w reads halve: 512 KB/CU (each w float4 feeds 4 b's in-register)
//   - x L2 re-read drops 16x -> 8x (OT 4 -> 8)
// A 4-way LDS reduction over the c-split partials finishes the block.
// All global streams stay contiguous (w rows 512 B, x rows 512 B, out rows
// 128 B per (b,o), single writer). LDS accesses are contiguous 512 B per
// half-wave -> conflict-free. 64 KB LDS, double-buffered c-chunks as in v3.
__global__ __launch_bounds__(512, 2) void nolc1d_kernel(
    const float* __restrict__ x,
    const float* __restrict__ w,
    float* __restrict__ out)
{
    // XCD swizzle: hw xcd = bid & 7. Put all 8 og-blocks sharing one pg's
    // x-slice (256 KB) on the same XCD so x is served from its L2.
    const int bid = blockIdx.x;
    const int xcd = bid & 7;
    const int r   = bid >> 3;
    const int og  = r & 7;                  // o-group 0..7
    const int pg  = xcd + 8 * (r >> 3);     // patch-group 0..31
    const int o0  = og * OT;
    const int pf0 = pg * PT;                // float4 column base

    const int t    = threadIdx.x;
    const int lane = t & 63;
    const int wv   = t >> 6;                         // wave 0..7
    const int g    = wv & 3;                         // b-group: b = 4g+bi
    const int cs   = ((wv >> 2) << 1) | (lane >> 5); // c-split 0..3 (c%4==cs)
    const int pp   = lane & 31;                      // patch within block

    // w tile chunk: [cl][o][pp] float4, cl = local c (8 per chunk).
    // 2 buffers x 2048 float4 = 64 KB. Also aliased as the reduction buffer.
    __shared__ float4 ws4[2][2048];

    const float4* __restrict__ x4 = (const float4*)x;
    const float4* __restrict__ w4 = (const float4*)w;

    // Stage c-chunk ch (c in [8ch, 8ch+8)) into buffer `buf`.
    // 2048 float4 / 512 threads = 4 each; wave-linear -> 512 B segments.
    auto stage = [&](int buf, int ch) {
        #pragma unroll
        for (int i = 0; i < 4; ++i) {
            const int L  = t + 512 * i;     // == (cl*8 + o)*32 + q
            const int cl = L >> 8;          // 0..7
            const int o  = (L >> 5) & 7;    // 0..7
            const int q  = L & 31;          // 0..31
            ws4[buf][L] =
                w4[((o0 + o) * CIN + (ch * 8 + cl)) * RS4 + pf0 + q];
        }
    };

    float acc[4][OT] = {};   // [bi][o] partial sums over this thread's c's
    const int xb = (4 * g * CIN + cs) * RS4 + pf0 + pp;

    stage(0, 0);
    __syncthreads();

    #pragma unroll
    for (int ch = 0; ch < 4; ++ch) {
        if (ch < 3) stage((ch + 1) & 1, ch + 1);   // prefetch next chunk
        const int buf = ch & 1;
        #pragma unroll
        for (int j = 0; j < 2; ++j) {
            const int c8 = 2 * ch + j;             // c = cs + 4*c8
            float4 xv[4];
            #pragma unroll
            for (int bi = 0; bi < 4; ++bi)
                xv[bi] = x4[xb + bi * (CIN * RS4) + c8 * 4 * RS4];
            const int cl = cs + 4 * j;             // local c in this chunk
            #pragma unroll
            for (int o = 0; o < OT; ++o) {
                const float4 wq = ws4[buf][(cl * 8 + o) * 32 + pp];
                #pragma unroll
                for (int bi = 0; bi < 4; ++bi)
                    acc[bi][o] += xv[bi].x * wq.x + xv[bi].y * wq.y +
                                  xv[bi].z * wq.z + xv[bi].w * wq.w;
            }
        }
        __syncthreads();   // readers done with buf AND next stage visible
    }

    // 4-way reduction over c-split partials. Reuse ws4 (all w reads done).
    // red[cs*1024 + (g*8+o)*32 + pp] packs the 4 b's of (g,o,pp) as a float4.
    float4* red = &ws4[0][0];
    #pragma unroll
    for (int o = 0; o < OT; ++o)
        red[cs * 1024 + (g * 8 + o) * 32 + pp] =
            make_float4(acc[0][o], acc[1][o], acc[2][o], acc[3][o]);
    __syncthreads();

    const float scale = 0.17677669529663687f;  // 1/sqrt(32)
    #pragma unroll
    for (int jj = 0; jj < 2; ++jj) {
        const int idx = t + 512 * jj;   // 0..1023 = (g2*8 + oo)*32 + p2
        const int g2  = idx >> 8;
        const int oo  = (idx >> 5) & 7;
        const int p2  = idx & 31;
        const float4 a = red[idx];
        const float4 b = red[idx + 1024];
        const float4 c = red[idx + 2048];
        const float4 d = red[idx + 3072];
        const int p = pf0 + p2;
        out[((4 * g2 + 0) * COUT + o0 + oo) * OUT_DIM + p] =
            (a.x + b.x + c.x + d.x) * scale;
        out[((4 * g2 + 1) * COUT + o0 + oo) * OUT_DIM + p] =
            (a.y + b.y + c.y + d.y) * scale;
        out[((4 * g2 + 2) * COUT + o0 + oo) * OUT_DIM + p] =
            (a.z + b.z + c.z + d.z) * scale;
        out[((4 * g2 + 3) * COUT + o0 + oo) * OUT_DIM + p] =
            (a.w + b.w + c.w + d.w) * scale;
    }
}

extern "C" void kernel_launch(void* const* d_in, const int* in_sizes, int n_in,
                              void* d_out, int out_size, void* d_ws, size_t ws_size,
                              hipStream_t stream) {
    const float* x = (const float*)d_in[0];   // [16][32][4096] fp32
    const float* w = (const float*)d_in[1];   // [64][32][4096] fp32
    float* out = (float*)d_out;               // [16][64][1024] fp32

    nolc1d_kernel<<<dim3(256), dim3(512), 0, stream>>>(x, w, out);
}

// Round 2
// 118.207 us; speedup vs baseline: 1.0181x; 1.0181x over previous
//
#include <hip/hip_runtime.h>

// Problem constants (fixed by reference)
#define BS      16
#define CIN     32
#define COUT    64
#define OUT_DIM 1024
#define RS4     1024           // float4 per (.,c) row of length 4096 floats

// Tiling: one float4 = one patch (K=4). Block = 8 o x 32 patches, all 16 b.
#define OT      8              // o per block
#define PT      32             // patches (float4 columns) per block
// grid = (64/OT) * (1024/PT) = 8 * 32 = 256 blocks = 1 per CU

// out[b,o,p] = (1/sqrt(32)) * sum_{c,k} x[b,c,4p+k] * w[o,c,4p+k]
//
// v5: v4 reuse scheme (4 b x 8 o x c-split-4 per thread) minus the register
// spills. v4 pinned VGPR_Count at the 128 cap and wrote 64 MB of scratch
// spills to HBM (WRITE_SIZE 68 MB vs 8 MB expected; VALUBusy 5.7%). The
// pressure came from stage()'s float4 staging data held in VGPRs across the
// software-pipelined chunk loop. v5 stages w with global_load_lds (width 16):
// direct HBM->LDS, no VGPR round-trip. LDS dest per wave-instruction is
// linear (wave-uniform base + lane*16B) as the HW requires; global source is
// per-lane. Everything else (streams, barriers, reduction) unchanged.
__global__ __launch_bounds__(512, 2) void nolc1d_kernel(
    const float* __restrict__ x,
    const float* __restrict__ w,
    float* __restrict__ out)
{
    // XCD swizzle: hw xcd = bid & 7. Put all 8 og-blocks sharing one pg's
    // x-slice (256 KB) on the same XCD so x is served from its L2.
    const int bid = blockIdx.x;
    const int xcd = bid & 7;
    const int r   = bid >> 3;
    const int og  = r & 7;                  // o-group 0..7
    const int pg  = xcd + 8 * (r >> 3);     // patch-group 0..31
    const int o0  = og * OT;
    const int pf0 = pg * PT;                // float4 column base

    const int t    = threadIdx.x;
    const int lane = t & 63;
    const int wv   = t >> 6;                         // wave 0..7
    const int g    = wv & 3;                         // b-group: b = 4g+bi
    const int cs   = ((wv >> 2) << 1) | (lane >> 5); // c-split 0..3 (c%4==cs)
    const int pp   = lane & 31;                      // patch within block

    // w tile chunk: [cl][o][pp] float4, cl = local c (8 per chunk).
    // 2 buffers x 2048 float4 = 64 KB. Also aliased as the reduction buffer.
    __shared__ float4 ws4[2][2048];

    const float4* __restrict__ x4 = (const float4*)x;
    const float4* __restrict__ w4 = (const float4*)w;

    // Stage c-chunk ch (c in [8ch, 8ch+8)) into buffer `buf` via
    // global_load_lds: per (wave, i) one 1 KB LDS segment, 16 B per lane.
    // L = t + 512*i = (cl*8 + o)*32 + q; within one wave-instruction cl is
    // constant (64 | 256) and lanes span two contiguous 512 B w rows.
    auto stage = [&](int buf, int ch) {
        #pragma unroll
        for (int i = 0; i < 4; ++i) {
            const int L  = t + 512 * i;
            const int cl = L >> 8;          // 0..7   (wave-uniform)
            const int o  = (L >> 5) & 7;    // 0..7
            const int q  = L & 31;          // 0..31
            const float4* src =
                &w4[((o0 + o) * CIN + (ch * 8 + cl)) * RS4 + pf0 + q];
            // wave-uniform LDS base; HW adds lane*16 B
            float4* dst = &ws4[buf][(wv << 6) + 512 * i];
            __builtin_amdgcn_global_load_lds(
                (const __attribute__((address_space(1))) void*)src,
                (__attribute__((address_space(3))) void*)dst,
                16, 0, 0);
        }
    };

    float acc[4][OT] = {};   // [bi][o] partial sums over this thread's c's
    const int xb = (4 * g * CIN + cs) * RS4 + pf0 + pp;

    stage(0, 0);
    __syncthreads();   // drains vmcnt -> buffer 0 visible

    #pragma unroll
    for (int ch = 0; ch < 4; ++ch) {
        if (ch < 3) stage((ch + 1) & 1, ch + 1);   // prefetch next chunk
        const int buf = ch & 1;
        #pragma unroll
        for (int j = 0; j < 2; ++j) {
            const int c8 = 2 * ch + j;             // c = cs + 4*c8
            float4 xv[4];
            #pragma unroll
            for (int bi = 0; bi < 4; ++bi)
                xv[bi] = x4[xb + bi * (CIN * RS4) + c8 * 4 * RS4];
            const int cl = cs + 4 * j;             // local c in this chunk
            #pragma unroll
            for (int o = 0; o < OT; ++o) {
                const float4 wq = ws4[buf][(cl * 8 + o) * 32 + pp];
                #pragma unroll
                for (int bi = 0; bi < 4; ++bi)
                    acc[bi][o] += xv[bi].x * wq.x + xv[bi].y * wq.y +
                                  xv[bi].z * wq.z + xv[bi].w * wq.w;
            }
        }
        __syncthreads();  // readers done with buf AND staged loads drained
    }

    // 4-way reduction over c-split partials. Reuse ws4 (all w reads done,
    // last barrier drained all outstanding staging loads).
    // red[cs*1024 + (g*8+o)*32 + pp] packs the 4 b's of (g,o,pp) as a float4.
    float4* red = &ws4[0][0];
    #pragma unroll
    for (int o = 0; o < OT; ++o)
        red[cs * 1024 + (g * 8 + o) * 32 + pp] =
            make_float4(acc[0][o], acc[1][o], acc[2][o], acc[3][o]);
    __syncthreads();

    const float scale = 0.17677669529663687f;  // 1/sqrt(32)
    #pragma unroll
    for (int jj = 0; jj < 2; ++jj) {
        const int idx = t + 512 * jj;   // 0..1023 = (g2*8 + oo)*32 + p2
        const int g2  = idx >> 8;
        const int oo  = (idx >> 5) & 7;
        const int p2  = idx & 31;
        const float4 a = red[idx];
        const float4 b = red[idx + 1024];
        const float4 c = red[idx + 2048];
        const float4 d = red[idx + 3072];
        const int p = pf0 + p2;
        out[((4 * g2 + 0) * COUT + o0 + oo) * OUT_DIM + p] =
            (a.x + b.x + c.x + d.x) * scale;
        out[((4 * g2 + 1) * COUT + o0 + oo) * OUT_DIM + p] =
            (a.y + b.y + c.y + d.y) * scale;
        out[((4 * g2 + 2) * COUT + o0 + oo) * OUT_DIM + p] =
            (a.z + b.z + c.z + d.z) * scale;
        out[((4 * g2 + 3) * COUT + o0 + oo) * OUT_DIM + p] =
            (a.w + b.w + c.w + d.w) * scale;
    }
}

extern "C" void kernel_launch(void* const* d_in, const int* in_sizes, int n_in,
                              void* d_out, int out_size, void* d_ws, size_t ws_size,
                              hipStream_t stream) {
    const float* x = (const float*)d_in[0];   // [16][32][4096] fp32
    const float* w = (const float*)d_in[1];   // [64][32][4096] fp32
    float* out = (float*)d_out;               // [16][64][1024] fp32

    nolc1d_kernel<<<dim3(256), dim3(512), 0, stream>>>(x, w, out);
}

// Round 3
// 89.429 us; speedup vs baseline: 1.3458x; 1.3218x over previous
//
#include <hip/hip_runtime.h>

// Problem constants (fixed by reference)
#define BS      16
#define CIN     32
#define COUT    64
#define OUT_DIM 1024
#define RS4     1024           // float4 per (.,c) row of length 4096 floats

// Tiling: one float4 = one patch (K=4). Block = 8 o x 32 patches, all 16 b.
#define OT      8              // o per block
#define PT      32             // patches (float4 columns) per block
// grid = (64/OT) * (1024/PT) = 8 * 32 = 256 blocks = 1 per CU

// out[b,o,p] = (1/sqrt(32)) * sum_{c,k} x[b,c,4p+k] * w[o,c,4p+k]
//
// v6: v4/v5 reuse scheme with the spill actually fixed, plus 2x occupancy.
//   - v4/v5 spilled because the fully-unrolled chunk loop let the scheduler
//     hoist x-loads across chunks (VGPR pinned at 128, WRITE_SIZE 67 MB of
//     scratch evictions, VALUBusy 6%). The chunk loop is now `unroll 1` and
//     each thread handles exactly ONE c per chunk (c-split 8-way), so the
//     live set is acc[4][8]=32 + xv[4]=16 + addresses ~= 80 VGPRs.
//   - 1024-thread blocks: 16 waves/CU = 4 waves/SIMD (2x v5) to hide x-load
//     latency; __launch_bounds__(1024,4) caps VGPRs at 128 which we fit.
//   - w staged HBM->LDS via global_load_lds (no VGPR round-trip), double
//     buffered; every global stream contiguous; single writer per out line.
//   - c-reduction: one intra-wave shfl_xor(32) (2-way) then a 4-way LDS tree
//     reusing the w buffers (64 KB) after the last chunk barrier.
__global__ __launch_bounds__(1024, 4) void nolc1d_kernel(
    const float* __restrict__ x,
    const float* __restrict__ w,
    float* __restrict__ out)
{
    // XCD swizzle: hw xcd = bid & 7. All 8 og-blocks sharing one pg's
    // x-slice (256 KB) land on the same XCD so x re-reads are L2-served.
    const int bid = blockIdx.x;
    const int xcd = bid & 7;
    const int r   = bid >> 3;
    const int og  = r & 7;                  // o-group 0..7
    const int pg  = xcd + 8 * (r >> 3);     // patch-group 0..31
    const int o0  = og * OT;
    const int pf0 = pg * PT;                // float4 column base

    const int t    = threadIdx.x;
    const int lane = t & 63;
    const int wv   = t >> 6;                 // wave 0..15
    const int g    = wv & 3;                 // b-group: b = 4g+bi
    const int csh  = wv >> 2;                // 0..3
    const int cs   = (csh << 1) | (lane >> 5); // c-split 0..7 (c%8==cs)
    const int pp   = lane & 31;              // patch (float4 col) in block

    // w tile chunk: [cl][o][pp] float4, cl = local c (8 per chunk).
    // 2 buffers x 2048 float4 = 64 KB. Aliased as reduction buffer at end.
    __shared__ float4 ws4[2][2048];

    const float4* __restrict__ x4 = (const float4*)x;
    const float4* __restrict__ w4 = (const float4*)w;

    // Stage c-chunk ch (c in [8ch, 8ch+8)) into buffer `buf` via
    // global_load_lds (16 B/lane, LDS dest = wave-uniform base + lane*16).
    // L = t + 1024*i = (cl*8 + o)*32 + q; cl is wave-uniform (64 | 256).
    auto stage = [&](int buf, int ch) {
        #pragma unroll
        for (int i = 0; i < 2; ++i) {
            const int L  = t + 1024 * i;
            const int cl = L >> 8;          // 0..7   (wave-uniform)
            const int o  = (L >> 5) & 7;    // 0..7
            const int q  = L & 31;          // 0..31
            const float4* src =
                &w4[((o0 + o) * CIN + (ch * 8 + cl)) * RS4 + pf0 + q];
            float4* dst = &ws4[buf][(L >> 6) << 6];   // lane-invariant base
            __builtin_amdgcn_global_load_lds(
                (const __attribute__((address_space(1))) void*)src,
                (__attribute__((address_space(3))) void*)dst,
                16, 0, 0);
        }
    };

    float acc[4][OT] = {};   // [bi][o] partials over this thread's 4 c's
    const int xb = ((4 * g) * CIN + cs) * RS4 + pf0 + pp;

    stage(0, 0);
    __syncthreads();   // drains vmcnt -> buffer 0 visible

    #pragma unroll 1   // keep live ranges within one chunk: no spills
    for (int ch = 0; ch < 4; ++ch) {
        if (ch < 3) stage((ch + 1) & 1, ch + 1);   // prefetch next chunk
        const int buf = ch & 1;
        // this thread's single c this chunk: c = ch*8 + cs  (local cl = cs)
        float4 xv[4];
        #pragma unroll
        for (int bi = 0; bi < 4; ++bi)
            xv[bi] = x4[xb + bi * (CIN * RS4) + ch * (8 * RS4)];
        #pragma unroll
        for (int o = 0; o < OT; ++o) {
            const float4 wq = ws4[buf][(cs * 8 + o) * 32 + pp];
            #pragma unroll
            for (int bi = 0; bi < 4; ++bi)
                acc[bi][o] += xv[bi].x * wq.x + xv[bi].y * wq.y +
                              xv[bi].z * wq.z + xv[bi].w * wq.w;
        }
        __syncthreads();  // readers done with buf AND staged loads drained
    }

    // c-reduction stage 1: 2-way intra-wave (partner lane^32 has the other
    // csl of this csh; same g, same pp).
    #pragma unroll
    for (int bi = 0; bi < 4; ++bi)
        #pragma unroll
        for (int o = 0; o < OT; ++o)
            acc[bi][o] += __shfl_xor(acc[bi][o], 32, 64);

    // c-reduction stage 2: 4-way over csh via LDS (reuse ws4: all w reads
    // completed before the last chunk barrier).
    // red[((csh*4+g)*8+o)*32+pp] packs the 4 b's of (g,o,pp) as float4.
    float4* red = &ws4[0][0];
    if (lane < 32) {
        #pragma unroll
        for (int o = 0; o < OT; ++o)
            red[((csh * 4 + g) * 8 + o) * 32 + pp] =
                make_float4(acc[0][o], acc[1][o], acc[2][o], acc[3][o]);
    }
    __syncthreads();

    const float scale = 0.17677669529663687f;  // 1/sqrt(32)
    const int idx = t;              // 0..1023 = (g2*8 + oo)*32 + p2
    const int g2  = idx >> 8;       // 0..3
    const int oo  = (idx >> 5) & 7; // 0..7
    const int p2  = idx & 31;       // 0..31
    const float4 a = red[idx];
    const float4 b = red[idx + 1024];
    const float4 c = red[idx + 2048];
    const float4 d = red[idx + 3072];
    const int p = pf0 + p2;
    out[((4 * g2 + 0) * COUT + o0 + oo) * OUT_DIM + p] =
        (a.x + b.x + c.x + d.x) * scale;
    out[((4 * g2 + 1) * COUT + o0 + oo) * OUT_DIM + p] =
        (a.y + b.y + c.y + d.y) * scale;
    out[((4 * g2 + 2) * COUT + o0 + oo) * OUT_DIM + p] =
        (a.z + b.z + c.z + d.z) * scale;
    out[((4 * g2 + 3) * COUT + o0 + oo) * OUT_DIM + p] =
        (a.w + b.w + c.w + d.w) * scale;
}

extern "C" void kernel_launch(void* const* d_in, const int* in_sizes, int n_in,
                              void* d_out, int out_size, void* d_ws, size_t ws_size,
                              hipStream_t stream) {
    const float* x = (const float*)d_in[0];   // [16][32][4096] fp32
    const float* w = (const float*)d_in[1];   // [64][32][4096] fp32
    float* out = (float*)d_out;               // [16][64][1024] fp32

    nolc1d_kernel<<<dim3(256), dim3(1024), 0, stream>>>(x, w, out);
}

// Round 4
// 87.519 us; speedup vs baseline: 1.3751x; 1.0218x over previous
//
#include <hip/hip_runtime.h>

// Problem constants (fixed by reference)
#define BS      16
#define CIN     32
#define COUT    64
#define OUT_DIM 1024
#define RS4     1024           // float4 per (.,c) row of length 4096 floats

// Tiling: one float4 = one patch (K=4). Block = 8 o x 32 patches, all 16 b.
#define OT      8              // o per block
#define PT      32             // patches (float4 columns) per block
// grid = (64/OT) * (1024/PT) = 8 * 32 = 256 blocks = 1 per CU

// out[b,o,p] = (1/sqrt(32)) * sum_{c,k} x[b,c,4p+k] * w[o,c,4p+k]
//
// v7: barrier-free main loop. v3 and v6 tied at ~23 us despite very
// different VMEM/LDS budgets -> shared bottleneck was the barrier-coupled
// w-staging pipeline: stage(ch+1) issued before the chunk's x loads means
// (FIFO vmcnt) the FMAs wait for the NEXT chunk's full HBM delivery, then
// __syncthreads drains vmcnt(0) for all 16 waves. ~90% of the kernel was
// serialized delivery windows (effective ~1.4 TB/s, vs 7 us HBM floor).
//
// Fix: w reuse within a block is only 4-way (the 4 b-groups). Skip LDS:
// each thread loads w fragments straight from global; the 4 sibling waves
// (same cs/lane, g=0..3) read identical addresses within a short window, so
// L1 (32 KB, = one chunk working set) / L2 absorb the redundancy. No
// main-loop barriers, no double buffer, no gload_lds: 16 independent waves
// of load+FMA; latency hidden by TLP, demand smoothed over the kernel.
// HBM traffic unchanged (w fetched once globally; x once per og-octet,
// L2-served via the XCD swizzle). Per-CU L1 traffic 768 KB ~= 5 us floor,
// under the 7 us HBM floor. Epilogue reduction identical to v6.
__global__ __launch_bounds__(1024, 4) void nolc1d_kernel(
    const float* __restrict__ x,
    const float* __restrict__ w,
    float* __restrict__ out)
{
    // XCD swizzle: hw xcd = bid & 7. All 8 og-blocks sharing one pg's
    // x-slice (256 KB) land on the same XCD so x re-reads are L2-served.
    const int bid = blockIdx.x;
    const int xcd = bid & 7;
    const int r   = bid >> 3;
    const int og  = r & 7;                  // o-group 0..7
    const int pg  = xcd + 8 * (r >> 3);     // patch-group 0..31
    const int o0  = og * OT;
    const int pf0 = pg * PT;                // float4 column base

    const int t    = threadIdx.x;
    const int lane = t & 63;
    const int wv   = t >> 6;                   // wave 0..15
    const int g    = wv & 3;                   // b-group: b = 4g+bi
    const int csh  = wv >> 2;                  // 0..3
    const int cs   = (csh << 1) | (lane >> 5); // c-split 0..7 (c%8==cs)
    const int pp   = lane & 31;                // patch (float4 col) in block

    // reduction buffer only (no staging): 4096 float4 = 64 KB
    __shared__ float4 red[4096];

    const float4* __restrict__ x4 = (const float4*)x;
    const float4* __restrict__ w4 = (const float4*)w;

    float acc[4][OT] = {};   // [bi][o] partials over this thread's 4 c's
    const int xb = ((4 * g) * CIN + cs) * RS4 + pf0 + pp;   // x[4g][cs][.]
    const int wb = (o0 * CIN + cs) * RS4 + pf0 + pp;        // w[o0][cs][.]

    // Main loop: this thread's 4 c's (c = cs + 8j). No barriers, no LDS.
    // unroll 2 keeps enough loads in flight for latency hiding without
    // blowing the 128-VGPR cap (live: acc 32 + 2x xv 16 + addr ~= 100).
    #pragma unroll 2
    for (int j = 0; j < 4; ++j) {
        float4 xv[4];
        #pragma unroll
        for (int bi = 0; bi < 4; ++bi)
            xv[bi] = x4[xb + bi * (CIN * RS4) + j * (8 * RS4)];
        #pragma unroll
        for (int o = 0; o < OT; ++o) {
            const float4 wq = w4[wb + o * (CIN * RS4) + j * (8 * RS4)];
            #pragma unroll
            for (int bi = 0; bi < 4; ++bi)
                acc[bi][o] += xv[bi].x * wq.x + xv[bi].y * wq.y +
                              xv[bi].z * wq.z + xv[bi].w * wq.w;
        }
    }

    // c-reduction stage 1: 2-way intra-wave (partner lane^32 has the other
    // cs of this csh; same g, same pp).
    #pragma unroll
    for (int bi = 0; bi < 4; ++bi)
        #pragma unroll
        for (int o = 0; o < OT; ++o)
            acc[bi][o] += __shfl_xor(acc[bi][o], 32, 64);

    // c-reduction stage 2: 4-way over csh via LDS.
    // red[((csh*4+g)*8+o)*32+pp] packs the 4 b's of (g,o,pp) as float4.
    if (lane < 32) {
        #pragma unroll
        for (int o = 0; o < OT; ++o)
            red[((csh * 4 + g) * 8 + o) * 32 + pp] =
                make_float4(acc[0][o], acc[1][o], acc[2][o], acc[3][o]);
    }
    __syncthreads();

    const float scale = 0.17677669529663687f;  // 1/sqrt(32)
    const int idx = t;              // 0..1023 = (g2*8 + oo)*32 + p2
    const int g2  = idx >> 8;       // 0..3
    const int oo  = (idx >> 5) & 7; // 0..7
    const int p2  = idx & 31;       // 0..31
    const float4 a = red[idx];
    const float4 b = red[idx + 1024];
    const float4 c = red[idx + 2048];
    const float4 d = red[idx + 3072];
    const int p = pf0 + p2;
    out[((4 * g2 + 0) * COUT + o0 + oo) * OUT_DIM + p] =
        (a.x + b.x + c.x + d.x) * scale;
    out[((4 * g2 + 1) * COUT + o0 + oo) * OUT_DIM + p] =
        (a.y + b.y + c.y + d.y) * scale;
    out[((4 * g2 + 2) * COUT + o0 + oo) * OUT_DIM + p] =
        (a.z + b.z + c.z + d.z) * scale;
    out[((4 * g2 + 3) * COUT + o0 + oo) * OUT_DIM + p] =
        (a.w + b.w + c.w + d.w) * scale;
}

extern "C" void kernel_launch(void* const* d_in, const int* in_sizes, int n_in,
                              void* d_out, int out_size, void* d_ws, size_t ws_size,
                              hipStream_t stream) {
    const float* x = (const float*)d_in[0];   // [16][32][4096] fp32
    const float* w = (const float*)d_in[1];   // [64][32][4096] fp32
    float* out = (float*)d_out;               // [16][64][1024] fp32

    nolc1d_kernel<<<dim3(256), dim3(1024), 0, stream>>>(x, w, out);
}

// Round 5
// 87.118 us; speedup vs baseline: 1.3815x; 1.0046x over previous
//
#include <hip/hip_runtime.h>

// Problem constants (fixed by reference)
#define BS      16
#define CIN     32
#define COUT    64
#define OUT_DIM 1024
#define RS4     1024           // float4 per (.,c) row of length 4096 floats

// v8: occupancy probe. v3/v6/v7 all land at 21-24 us despite 2x different
// byte budgets (static floors: HBM 7 us, L1 5-7 us, VALU 1.7 us) -> the
// family is latency-bound, and all variants shared waves/SIMD = 4 (128-VGPR
// tiles, one fat block per CU). v8 trades register reuse for TLP:
//   - per-thread tile 4b x 4o (acc = 16 VGPRs), c-split 8 -> ~70 VGPRs
//   - 256-thread blocks, __launch_bounds__(256,6): 6 waves/SIMD resident
//     (1.5x), 8 blocks/CU queued -> smooth demand, robust to dispatch skew
//   - delivered bytes rise to ~1 MB/CU (x served 16x, w 4x from L2) but
//     that floor (~7 us) matches the HBM floor, so the price is affordable
// Block tile: 4 b x 4 o x 32 patches. Grid = 4 bs x 16 og x 32 pg = 2048.
// XCD swizzle: all 64 blocks (16 og x 4 bs) sharing one pg's x/w slices
// land on the same XCD -> redundancy L2-served.
// No main-loop LDS/barriers (v7 lesson); 8 KB LDS reduction at the end.
__global__ __launch_bounds__(256, 6) void nolc1d_kernel(
    const float* __restrict__ x,
    const float* __restrict__ w,
    float* __restrict__ out)
{
    // bid = xcd + 8*j ; j = og | bs<<4 | pghi<<6  -> pg = xcd + 8*pghi
    const int bid = blockIdx.x;
    const int xcd = bid & 7;
    const int j   = bid >> 3;
    const int og  = j & 15;                 // o-group 0..15 (4 o each)
    const int bs  = (j >> 4) & 3;           // b-group 0..3  (4 b each)
    const int pg  = xcd + 8 * (j >> 6);     // patch-group 0..31 (32 p each)
    const int o0  = og * 4;
    const int b0  = bs * 4;
    const int pf0 = pg * 32;                // float4 column base

    const int t    = threadIdx.x;
    const int lane = t & 63;
    const int wv   = t >> 6;                // wave 0..3
    const int cs   = t >> 5;                // c-split 0..7 (c % 8 == cs)
    const int pp   = t & 31;                // patch (float4 col) in block

    const float4* __restrict__ x4 = (const float4*)x;
    const float4* __restrict__ w4 = (const float4*)w;

    float acc[4][4] = {};                   // [bi][o]

    // Main loop: this thread's 4 c's (c = cs + 8k). No barriers, no LDS.
    // unroll 1: live set stays acc16 + xv16 + w-in-flight ~16 + addr -> ~70
    // VGPRs, under the (256,6) cap of 85. Latency hidden by 6 waves/SIMD.
    #pragma unroll 1
    for (int k = 0; k < 4; ++k) {
        const int c = cs + 8 * k;
        float4 xv[4];
        #pragma unroll
        for (int bi = 0; bi < 4; ++bi)
            xv[bi] = x4[((b0 + bi) * CIN + c) * RS4 + pf0 + pp];
        #pragma unroll
        for (int o = 0; o < 4; ++o) {
            const float4 wq = w4[((o0 + o) * CIN + c) * RS4 + pf0 + pp];
            #pragma unroll
            for (int bi = 0; bi < 4; ++bi)
                acc[bi][o] += xv[bi].x * wq.x + xv[bi].y * wq.y +
                              xv[bi].z * wq.z + xv[bi].w * wq.w;
        }
    }

    // c-reduction stage 1: lane^32 holds cs^1 (same pp) -> 2-way in-wave.
    #pragma unroll
    for (int bi = 0; bi < 4; ++bi)
        #pragma unroll
        for (int o = 0; o < 4; ++o)
            acc[bi][o] += __shfl_xor(acc[bi][o], 32, 64);

    // c-reduction stage 2: 4-way over waves via LDS (8 KB).
    // red[wv][bi][o][pp]: per (bi,o) a contiguous 32-float run -> no bank
    // conflicts on write (lanes 0..31) or read (2 contiguous runs/wave).
    __shared__ float red[4][4][4][32];
    if (lane < 32) {
        #pragma unroll
        for (int bi = 0; bi < 4; ++bi)
            #pragma unroll
            for (int o = 0; o < 4; ++o)
                red[wv][bi][o][pp] = acc[bi][o];
    }
    __syncthreads();

    const float scale = 0.17677669529663687f;  // 1/sqrt(32)
    #pragma unroll
    for (int rep = 0; rep < 2; ++rep) {
        const int idx = t + 256 * rep;      // 0..511 = (b*4 + o)*32 + p2
        const int b   = idx >> 7;
        const int o   = (idx >> 5) & 3;
        const int p2  = idx & 31;
        const float s = red[0][b][o][p2] + red[1][b][o][p2] +
                        red[2][b][o][p2] + red[3][b][o][p2];
        out[((size_t)(b0 + b) * COUT + o0 + o) * OUT_DIM + pg * 32 + p2] =
            s * scale;
    }
}

extern "C" void kernel_launch(void* const* d_in, const int* in_sizes, int n_in,
                              void* d_out, int out_size, void* d_ws, size_t ws_size,
                              hipStream_t stream) {
    const float* x = (const float*)d_in[0];   // [16][32][4096] fp32
    const float* w = (const float*)d_in[1];   // [64][32][4096] fp32
    float* out = (float*)d_out;               // [16][64][1024] fp32

    nolc1d_kernel<<<dim3(2048), dim3(256), 0, stream>>>(x, w, out);
}